// Round 2
// baseline (749.891 us; speedup 1.0000x reference)
//
#include <hip/hip_runtime.h>
#include <hip/hip_bf16.h>
#include <stdint.h>

typedef _Float16 f16x8 __attribute__((ext_vector_type(8)));
typedef float    f32x4 __attribute__((ext_vector_type(4)));

// async 16-B global->LDS DMA: per-lane global src, dest = wave-uniform base + lane*16
#define GLDS16(gptr, lptr) \
  __builtin_amdgcn_global_load_lds((const __attribute__((address_space(1))) void*)(gptr), \
                                   (__attribute__((address_space(3))) void*)(lptr), 16, 0, 0)

// counted vmcnt wait (literal immediate), full memory clobber so LDS reads /
// DMA issues cannot cross it (rule #18)
#define WAITV(N) asm volatile("s_waitcnt vmcnt(" #N ")" ::: "memory")

// ---- tiled ("DMA-image") activation layout ----
// element (row, col) lives at:
//   addr = ((rb*4 + c)*8 + sub)*512 + r*8 + j     (halves)
// with rb=row>>6, r=row&63, c=col>>6, sub=(col>>3)&7, j=col&7.
// One (rb,c,sub) unit = 64 rows x 8 cols = 512 halves = 1 KB contiguous,
// exactly the order gru_cell's A-DMA fills LDS -> fully coalesced loads.
__device__ __forceinline__ int tile_off(int rb, int c, int sub) {
    return ((rb * 4 + c) * 8 + sub) * 512;
}

// WP layout: [c(8)][d0b(4)][g(4)][sub(8)][nl(64)][j(8)] halves.
// element = W(group g, dim d = d0b*64+nl, k = c*64+sub*8+j)
// Block 2048 packs BC[1024]: [d]=bih[d]+bhh[d], [256+d]=bih[256+d]+bhh[256+d],
//                            [512+d]=bih[512+d], [768+d]=bhh[512+d]
__global__ __launch_bounds__(256) void prepack_weights(
    const float* __restrict__ Wih, const float* __restrict__ Whh,
    const float* __restrict__ bih, const float* __restrict__ bhh,
    _Float16* __restrict__ WP, float* __restrict__ BC)
{
    if (blockIdx.x == 2048) {
        int i = threadIdx.x;
        BC[i]       = bih[i] + bhh[i];
        BC[256 + i] = bih[256 + i] + bhh[256 + i];
        BC[512 + i] = bih[512 + i];
        BC[768 + i] = bhh[512 + i];
        return;
    }
    int idx = blockIdx.x * 256 + threadIdx.x;   // 524288 total
    int j   = idx & 7;
    int nl  = (idx >> 3) & 63;
    int sub = (idx >> 9) & 7;
    int g   = (idx >> 12) & 3;
    int d0b = (idx >> 14) & 3;
    int c   = idx >> 16;
    int k = c * 64 + sub * 8 + j;
    int d = d0b * 64 + nl;
    float v = 0.f;
    if (g == 0)      v = (k < 256) ? Wih[d * 256 + k]         : Whh[d * 256 + (k - 256)];
    else if (g == 1) v = (k < 256) ? Wih[(256 + d) * 256 + k] : Whh[(256 + d) * 256 + (k - 256)];
    else if (g == 2) v = (k < 256) ? Wih[(512 + d) * 256 + k] : 0.f;
    else             v = (k >= 256) ? Whh[(512 + d) * 256 + (k - 256)] : 0.f;
    WP[idx] = (_Float16)v;
}

// fp32 leaf -> fp16, split even/odd rows into TILED XE / XO buffers.
__global__ __launch_bounds__(256) void convert_split(
    const float* __restrict__ leaf, _Float16* __restrict__ XE, _Float16* __restrict__ XO)
{
    int g = blockIdx.x * 256 + threadIdx.x;     // 131072 rows * 32 units
    int u = g & 31;                              // 16-B col unit: cols u*8 .. u*8+7
    int row = g >> 5;
    const float* src = leaf + (size_t)row * 256 + u * 8;
    float4 a = *(const float4*)src;
    float4 b = *(const float4*)(src + 4);
    f16x8 p;
    p[0] = (_Float16)a.x; p[1] = (_Float16)a.y; p[2] = (_Float16)a.z; p[3] = (_Float16)a.w;
    p[4] = (_Float16)b.x; p[5] = (_Float16)b.y; p[6] = (_Float16)b.z; p[7] = (_Float16)b.w;
    int ro = row >> 1;
    _Float16* dst = (row & 1) ? XO : XE;
    *(f16x8*)(dst + tile_off(ro >> 6, u >> 3, u & 7) + (ro & 63) * 8) = p;
}

// GRU cell, half-chunk pipelined (T3+T4+T5):
//   stream of NH = 2*nch half-chunks; 4 half-buffers for A and B;
//   prefetch depth 3 halves; per half:
//     s_waitcnt vmcnt(2*DPW)  (counted - 2 halves stay in flight)
//     s_barrier               (half h fully in LDS; buffer (h-1)&3 freed)
//     issue DMA for half h+3  (into buffer (h+3)&3 == (h-1)&3)
//     ds_read frags; setprio(1); 24 MFMA; setprio(0)
// cell1 (Hout != null): h' -> Hout tiles       (hin = Hsrc or 0)
// cell2 (Hout == null): E=0.5(hin+h') -> Ee/Eo tiles; HP = pair-avg(h') tiles
template<int MT, bool SWIZ>
__global__ __launch_bounds__(256, (MT == 8) ? 2 : 3) void gru_cell(
    const _Float16* __restrict__ Xsrc,
    const _Float16* __restrict__ Hsrc,
    const _Float16* __restrict__ WP,
    const float* __restrict__ BC,
    _Float16* __restrict__ Hout,
    _Float16* __restrict__ Ee, _Float16* __restrict__ Eo, _Float16* __restrict__ HP,
    int M)
{
    (void)M;
    constexpr int AROW  = MT * 16 * 8;        // halves per A sub-column unit
    constexpr int AHALF = 4 * AROW;           // half-buffer: 4 subs (MT=8: 8 KB)
    constexpr int BROW  = 512;                // 64 dims * 8 halves
    constexpr int BHALF = 12 * BROW;          // 3 groups x 4 subs = 12 KB
    __shared__ __align__(16) _Float16 Alds[4 * AHALF];   // MT=8: 32 KB
    __shared__ __align__(16) _Float16 Blds[4 * BHALF];   // 48 KB  (total 80 KB)

    const int tid  = threadIdx.x;
    int bm, d0b;
    if (SWIZ) {  // siblings (same bm, 4 d0b) share blockIdx%8 -> same XCD
        int xcd = blockIdx.x & 7, slot = blockIdx.x >> 3;
        d0b = slot & 3;
        bm  = (slot >> 2) * 8 + xcd;
    } else {
        bm = blockIdx.x >> 2; d0b = blockIdx.x & 3;
    }
    const int wave = tid >> 6, lane = tid & 63;
    const int quad = lane >> 4, lo = lane & 15;

    const bool has_h = (Hsrc != nullptr);
    const int NH = has_h ? 16 : 8;            // half-chunks

    f32x4 acc[MT][4];
#pragma unroll
    for (int a = 0; a < MT; ++a)
#pragma unroll
        for (int b = 0; b < 4; ++b) acc[a][b] = (f32x4){0.f, 0.f, 0.f, 0.f};
    float hinv[MT][4];

    // per-wave DMA issues per half: 3 B + MT/4 A  (MT=8: 5, MT=4: 4)
    auto issueHalf = [&](int h) {
        const int hb = h & 3, par = h & 1, c = h >> 1;
        const size_t cb = (size_t)(c * 4 + d0b) * 4;
        _Float16* dstb = Blds + hb * BHALF;
#pragma unroll
        for (int i = 0; i < 3; ++i) {
            int bi = wave * 3 + i;            // 12 units: 3 slots x 4 subs
            int slot = bi >> 2, s = bi & 3;
            int g = (slot == 2) ? ((c < 4) ? 2 : 3) : slot;
            GLDS16(WP + ((cb + g) * 8 + par * 4 + s) * 512 + lane * 8,
                   dstb + (slot * 4 + s) * BROW);
        }
        const _Float16* base = (c < 4) ? Xsrc : Hsrc;
        const int cc = c & 3;
        _Float16* Ab = Alds + hb * AHALF;
        constexpr int APW = MT / 4;
#pragma unroll
        for (int i = 0; i < APW; ++i) {
            int ai = wave * APW + i;          // MT=8: 8 units (4 subs x 2 mh)
            int s  = (MT == 8) ? (ai >> 1) : ai;
            int mh = (MT == 8) ? (ai & 1) : 0;
            GLDS16(base + tile_off(bm * (MT / 4) + mh, cc, par * 4 + s) + lane * 8,
                   Ab + s * AROW + mh * 512);
        }
    };

    issueHalf(0); issueHalf(1); issueHalf(2);

    for (int h = 0; h < NH; ++h) {
        // counted drain: only half h retires; halves h+1,h+2 stay in flight
        if (h < NH - 2)       { if (MT == 8) WAITV(10); else WAITV(8); }
        else if (h == NH - 2) { if (MT == 8) WAITV(5);  else WAITV(4); }
        else                  WAITV(0);
        __builtin_amdgcn_s_barrier();
        __builtin_amdgcn_sched_barrier(0);
        if (h + 3 < NH) issueHalf(h + 3);

        const _Float16* Bb = Blds + (h & 3) * BHALF;
        const _Float16* Ab = Alds + (h & 3) * AHALF;
        const _Float16* brow = Bb + quad * BROW + (wave * 16 + lo) * 8;
        f16x8 b0 = *(const f16x8*)(brow);
        f16x8 b1 = *(const f16x8*)(brow + 4 * BROW);
        f16x8 b2 = *(const f16x8*)(brow + 8 * BROW);
        f16x8 af[MT];
#pragma unroll
        for (int mt = 0; mt < MT; ++mt)
            af[mt] = *(const f16x8*)(Ab + quad * AROW + (mt * 16 + lo) * 8);
        const int c = h >> 1;
        __builtin_amdgcn_s_setprio(1);
#pragma unroll
        for (int mt = 0; mt < MT; ++mt)
            acc[mt][0] = __builtin_amdgcn_mfma_f32_16x16x32_f16(af[mt], b0, acc[mt][0], 0, 0, 0);
#pragma unroll
        for (int mt = 0; mt < MT; ++mt)
            acc[mt][1] = __builtin_amdgcn_mfma_f32_16x16x32_f16(af[mt], b1, acc[mt][1], 0, 0, 0);
        if (c < 4) {
#pragma unroll
            for (int mt = 0; mt < MT; ++mt)
                acc[mt][2] = __builtin_amdgcn_mfma_f32_16x16x32_f16(af[mt], b2, acc[mt][2], 0, 0, 0);
        } else {
#pragma unroll
            for (int mt = 0; mt < MT; ++mt)
                acc[mt][3] = __builtin_amdgcn_mfma_f32_16x16x32_f16(af[mt], b2, acc[mt][3], 0, 0, 0);
        }
        __builtin_amdgcn_s_setprio(0);

        // capture hin while this half holds our dim-columns of Hsrc.
        // waves 0,1 own subs 0-3 (even half); waves 2,3 own subs 4-7 (odd half)
        if (has_h && c == 4 + d0b && (wave >> 1) == (h & 1)) {
            const int colw = wave * 16 + lo;
            const int sl = (colw >> 3) & 3, j = colw & 7;
#pragma unroll
            for (int mt = 0; mt < MT; ++mt)
#pragma unroll
                for (int r = 0; r < 4; ++r)
                    hinv[mt][r] = (float)Ab[sl * AROW + (mt * 16 + quad * 4 + r) * 8 + j];
        }
    }

    // ---- epilogue: compute h', stage via Alds, coalesced tiled stores ----
    const int ld = wave * 16 + lo;
    const int d  = d0b * 64 + ld;
    const float brz0 = BC[d];        // bir+bhr
    const float brz1 = BC[256 + d];  // biz+bhz
    const float bni  = BC[512 + d];  // bin
    const float bnh  = BC[768 + d];  // bhn
    constexpr int SROW = 72;         // staging row stride (16-B aligned rows)
    constexpr int PR   = MT * 8;     // pair-rows per block
    __syncthreads();                 // all waves done reading Alds chunk data
#pragma unroll
    for (int mt = 0; mt < MT; ++mt) {
        const int lr0 = mt * 16 + quad * 4;
        float hq[4];
#pragma unroll
        for (int r = 0; r < 4; ++r) {
            float hin = has_h ? hinv[mt][r] : 0.f;
            float rg = 1.f / (1.f + __expf(-(acc[mt][0][r] + brz0)));
            float zg = 1.f / (1.f + __expf(-(acc[mt][1][r] + brz1)));
            float ex = __expf(2.f * (acc[mt][2][r] + bni + rg * (acc[mt][3][r] + bnh)));
            float nv = 1.f - 2.f / (ex + 1.f);
            hq[r] = (1.f - zg) * nv + zg * hin;
            int lr = lr0 + r;
            if (Hout) {
                Alds[lr * SROW + ld] = (_Float16)hq[r];
            } else {
                Alds[(((lr & 1) * PR) + (lr >> 1)) * SROW + ld] =
                    (_Float16)(0.5f * (hin + hq[r]));
            }
        }
        if (!Hout) {
            Alds[(2 * PR + (lr0 >> 1)) * SROW + ld]     = (_Float16)(0.5f * (hq[0] + hq[1]));
            Alds[(2 * PR + (lr0 >> 1) + 1) * SROW + ld] = (_Float16)(0.5f * (hq[2] + hq[3]));
        }
    }
    __syncthreads();

    if (Hout) {
        constexpr int NU = MT * 128;                 // 16-B units (MT*16 rows x 64 dims)
#pragma unroll
        for (int i = 0; i < NU / 256; ++i) {
            int uid = i * 256 + tid;
            int r = uid & 63, sub = (uid >> 6) & 7, mh = uid >> 9;
            f16x8 v = *(const f16x8*)&Alds[(mh * 64 + r) * SROW + sub * 8];
            *(f16x8*)(Hout + tile_off(bm * (MT / 4) + mh, d0b, sub) + r * 8) = v;
        }
    } else {
        constexpr int NU = 3 * PR * 8;               // Ee, Eo, HP units
        const int rbE  = (MT == 8) ? bm : (bm >> 1);
        const int roff = (MT == 8) ? 0 : (bm & 1) * 32;
#pragma unroll
        for (int i = 0; i < NU / 256; ++i) {
            int uid = i * 256 + tid;
            int pr   = uid & (PR - 1);
            int rest = uid / PR;
            int sub = rest & 7, buf = rest >> 3;     // 0=Ee 1=Eo 2=HP
            f16x8 v = *(const f16x8*)&Alds[(buf * PR + pr) * SROW + sub * 8];
            _Float16* dst = (buf == 0) ? Ee : (buf == 1) ? Eo : HP;
            *(f16x8*)(dst + tile_off(rbE, d0b, sub) + (roff + pr) * 8) = v;
        }
    }
}

__global__ __launch_bounds__(256) void final_out(
    const _Float16* __restrict__ XE, const _Float16* __restrict__ XO,
    float* __restrict__ out)
{
    int i = blockIdx.x * 256 + threadIdx.x;   // 8192
    int j = i >> 8, col = i & 255;
    const _Float16* src = (j & 1) ? XO : XE;
    int r = j >> 1;                            // 0..15, all in tile 0
    out[i] = (float)src[tile_off(0, col >> 6, (col >> 3) & 7) + r * 8 + (col & 7)];
}

extern "C" void kernel_launch(void* const* d_in, const int* in_sizes, int n_in,
                              void* d_out, int out_size, void* d_ws, size_t ws_size,
                              hipStream_t stream) {
    const float* leaf = (const float*)d_in[0];
    const float* Wih  = (const float*)d_in[1];
    const float* Whh  = (const float*)d_in[2];
    const float* bih  = (const float*)d_in[3];
    const float* bhh  = (const float*)d_in[4];

    char* ws = (char*)d_ws;
    _Float16* WPp = (_Float16*)ws;                         //  1 MB
    _Float16* XAe = (_Float16*)(ws + (1ull  << 20));       // 32 MB
    _Float16* XAo = (_Float16*)(ws + (33ull << 20));       // 32 MB
    _Float16* XBe = (_Float16*)(ws + (65ull << 20));       // 16 MB
    _Float16* XBo = (_Float16*)(ws + (81ull << 20));       // 16 MB
    _Float16* H1  = (_Float16*)(ws + (97ull << 20));       // 32 MB
    _Float16* HPb = (_Float16*)(ws + (129ull << 20));      // 16 MB
    float*    BCp = (float*)(ws + (145ull << 20));         //  4 KB

    prepack_weights<<<2049, 256, 0, stream>>>(Wih, Whh, bih, bhh, WPp, BCp);
    convert_split<<<16384, 256, 0, stream>>>(leaf, XAe, XAo);

    _Float16 *XeC = XAe, *XoC = XAo, *XeN = XBe, *XoN = XBo;
    const _Float16* hp = nullptr;
    int M = 65536;
    for (int lev = 0; lev < 12; ++lev) {
        if (M >= 8192) {
            int grid = (M / 128) * 4;
            gru_cell<8, true><<<grid, 256, 0, stream>>>(XeC, hp, WPp, BCp,
                                                        H1, nullptr, nullptr, nullptr, M);
            gru_cell<8, true><<<grid, 256, 0, stream>>>(XoC, H1, WPp, BCp,
                                                        nullptr, XeN, XoN, HPb, M);
        } else {
            int nbm = (M + 63) / 64;
            int grid = nbm * 4;
            if ((nbm & 7) == 0) {
                gru_cell<4, true><<<grid, 256, 0, stream>>>(XeC, hp, WPp, BCp,
                                                            H1, nullptr, nullptr, nullptr, M);
                gru_cell<4, true><<<grid, 256, 0, stream>>>(XoC, H1, WPp, BCp,
                                                            nullptr, XeN, XoN, HPb, M);
            } else {
                gru_cell<4, false><<<grid, 256, 0, stream>>>(XeC, hp, WPp, BCp,
                                                             H1, nullptr, nullptr, nullptr, M);
                gru_cell<4, false><<<grid, 256, 0, stream>>>(XoC, H1, WPp, BCp,
                                                             nullptr, XeN, XoN, HPb, M);
            }
        }
        hp = HPb;
        _Float16* t;
        t = XeC; XeC = XeN; XeN = t;
        t = XoC; XoC = XoN; XoN = t;
        M >>= 1;
    }
    final_out<<<32, 256, 0, stream>>>(XeC, XoC, (float*)d_out);
}

// Round 3
// 666.060 us; speedup vs baseline: 1.1259x; 1.1259x over previous
//
#include <hip/hip_runtime.h>
#include <hip/hip_bf16.h>
#include <stdint.h>

typedef _Float16 f16x8 __attribute__((ext_vector_type(8)));
typedef float    f32x4 __attribute__((ext_vector_type(4)));

// async 16-B global->LDS DMA: per-lane global src, dest = wave-uniform base + lane*16
#define GLDS16(gptr, lptr) \
  __builtin_amdgcn_global_load_lds((const __attribute__((address_space(1))) void*)(gptr), \
                                   (__attribute__((address_space(3))) void*)(lptr), 16, 0, 0)

// counted vmcnt wait (literal immediate), full memory clobber so LDS reads /
// DMA issues cannot cross it (rule #18)
#define WAITV(N) asm volatile("s_waitcnt vmcnt(" #N ")" ::: "memory")

// ---- tiled ("DMA-image") activation layout ----
// element (row, col) lives at:
//   addr = ((rb*4 + c)*8 + sub)*512 + r*8 + j     (halves)
// with rb=row>>6, r=row&63, c=col>>6, sub=(col>>3)&7, j=col&7.
// One (rb,c,sub) unit = 64 rows x 8 cols = 512 halves = 1 KB contiguous,
// exactly the order gru_cell's A-DMA fills LDS -> fully coalesced loads.
__device__ __forceinline__ int tile_off(int rb, int c, int sub) {
    return ((rb * 4 + c) * 8 + sub) * 512;
}

// WP layout: [c(8)][d0b(4)][g(4)][sub(8)][nl(64)][j(8)] halves.
// element = W(group g, dim d = d0b*64+nl, k = c*64+sub*8+j)
// Block 2048 packs BC[1024]: [d]=bih[d]+bhh[d], [256+d]=bih[256+d]+bhh[256+d],
//                            [512+d]=bih[512+d], [768+d]=bhh[512+d]
__global__ __launch_bounds__(256) void prepack_weights(
    const float* __restrict__ Wih, const float* __restrict__ Whh,
    const float* __restrict__ bih, const float* __restrict__ bhh,
    _Float16* __restrict__ WP, float* __restrict__ BC)
{
    if (blockIdx.x == 2048) {
        int i = threadIdx.x;
        BC[i]       = bih[i] + bhh[i];
        BC[256 + i] = bih[256 + i] + bhh[256 + i];
        BC[512 + i] = bih[512 + i];
        BC[768 + i] = bhh[512 + i];
        return;
    }
    int idx = blockIdx.x * 256 + threadIdx.x;   // 524288 total
    int j   = idx & 7;
    int nl  = (idx >> 3) & 63;
    int sub = (idx >> 9) & 7;
    int g   = (idx >> 12) & 3;
    int d0b = (idx >> 14) & 3;
    int c   = idx >> 16;
    int k = c * 64 + sub * 8 + j;
    int d = d0b * 64 + nl;
    float v = 0.f;
    if (g == 0)      v = (k < 256) ? Wih[d * 256 + k]         : Whh[d * 256 + (k - 256)];
    else if (g == 1) v = (k < 256) ? Wih[(256 + d) * 256 + k] : Whh[(256 + d) * 256 + (k - 256)];
    else if (g == 2) v = (k < 256) ? Wih[(512 + d) * 256 + k] : 0.f;
    else             v = (k >= 256) ? Whh[(512 + d) * 256 + (k - 256)] : 0.f;
    WP[idx] = (_Float16)v;
}

// fp32 leaf -> fp16, split even/odd rows into TILED XE / XO buffers.
__global__ __launch_bounds__(256) void convert_split(
    const float* __restrict__ leaf, _Float16* __restrict__ XE, _Float16* __restrict__ XO)
{
    int g = blockIdx.x * 256 + threadIdx.x;     // 131072 rows * 32 units
    int u = g & 31;                              // 16-B col unit: cols u*8 .. u*8+7
    int row = g >> 5;
    const float* src = leaf + (size_t)row * 256 + u * 8;
    float4 a = *(const float4*)src;
    float4 b = *(const float4*)(src + 4);
    f16x8 p;
    p[0] = (_Float16)a.x; p[1] = (_Float16)a.y; p[2] = (_Float16)a.z; p[3] = (_Float16)a.w;
    p[4] = (_Float16)b.x; p[5] = (_Float16)b.y; p[6] = (_Float16)b.z; p[7] = (_Float16)b.w;
    int ro = row >> 1;
    _Float16* dst = (row & 1) ? XO : XE;
    *(f16x8*)(dst + tile_off(ro >> 6, u >> 3, u & 7) + (ro & 63) * 8) = p;
}

// GRU cell. A (tiled-coalesced) and B staged via async DMA into LDS.
//   MT=8 (big levels): double-buffered, ONE __syncthreads per chunk
//     (round-1 proven structure: barrier -> issue(c+1) -> compute(c)).
//   MT=4 (tail levels, latency-bound small grids): TRIPLE-buffered,
//     depth-2 prefetch with counted vmcnt so the per-chunk DMA chain
//     (the tail's critical path) is hidden under two compute phases:
//     WAITV(8) -> s_barrier -> issue(c+2) -> compute(c).
// cell1 (Hout != null): h' -> Hout tiles       (hin = Hsrc or 0)
// cell2 (Hout == null): E=0.5(hin+h') -> Ee/Eo tiles; HP = pair-avg(h') tiles
template<int MT, bool SWIZ>
__global__ __launch_bounds__(256, (MT == 8) ? 2 : 3) void gru_cell(
    const _Float16* __restrict__ Xsrc,
    const _Float16* __restrict__ Hsrc,
    const _Float16* __restrict__ WP,
    const float* __restrict__ BC,
    _Float16* __restrict__ Hout,
    _Float16* __restrict__ Ee, _Float16* __restrict__ Eo, _Float16* __restrict__ HP,
    int M)
{
    (void)M;
    constexpr int NBUF = (MT == 8) ? 2 : 3;
    constexpr int AROW = MT * 16 * 8;       // halves per A sub-row
    constexpr int ASZ  = 8 * AROW;          // MT=8: 16 KB, MT=4: 8 KB
    constexpr int BROW = 512;               // 64 dims * 8 halves
    constexpr int BSZ  = 3 * 8 * BROW;      // 24 KB
    __shared__ __align__(16) _Float16 Alds[NBUF * ASZ];   // MT=8: 32 KB, MT=4: 24 KB
    __shared__ __align__(16) _Float16 Blds[NBUF * BSZ];   // MT=8: 48 KB, MT=4: 72 KB

    const int tid  = threadIdx.x;
    int bm, d0b;
    if (SWIZ) {  // siblings (same bm, 4 d0b) share blockIdx%8 -> same XCD
        int xcd = blockIdx.x & 7, slot = blockIdx.x >> 3;
        d0b = slot & 3;
        bm  = (slot >> 2) * 8 + xcd;
    } else {
        bm = blockIdx.x >> 2; d0b = blockIdx.x & 3;
    }
    const int wave = tid >> 6, lane = tid & 63;
    const int quad = lane >> 4, lo = lane & 15;

    const bool has_h = (Hsrc != nullptr);
    const int nch = has_h ? 8 : 4;

    f32x4 acc[MT][4];
#pragma unroll
    for (int a = 0; a < MT; ++a)
#pragma unroll
        for (int b = 0; b < 4; ++b) acc[a][b] = (f32x4){0.f, 0.f, 0.f, 0.f};
    float hinv[MT][4];

    auto issueB = [&](int c, int buf) {   // 24 DMA issues (3 groups x 8 subs), 6/wave
        const size_t cb = (size_t)(c * 4 + d0b) * 4;
        _Float16* dstb = Blds + buf * BSZ;
#pragma unroll
        for (int i = 0; i < 6; ++i) {
            int bi = wave * 6 + i;
            int slot = bi >> 3, sub = bi & 7;
            int g = (slot == 2) ? ((c < 4) ? 2 : 3) : slot;
            GLDS16(WP + ((cb + g) * 8 + sub) * 512 + lane * 8,
                   dstb + (slot * 8 + sub) * BROW);
        }
    };

    auto issueA = [&](int c, int buf) {   // 2*MT coalesced 1-KB DMA issues, MT/2 per wave
        const _Float16* base = (c < 4) ? Xsrc : Hsrc;
        const int cc = c & 3;
        _Float16* Ab = Alds + buf * ASZ;
        constexpr int ND = MT / 2;
#pragma unroll
        for (int i = 0; i < ND; ++i) {
            int ai = wave * ND + i;
            int sub = (MT == 8) ? (ai >> 1) : ai;
            int mh  = (MT == 8) ? (ai & 1) : 0;
            GLDS16(base + tile_off(bm * (MT / 4) + mh, cc, sub) + lane * 8,
                   Ab + sub * AROW + mh * 512);
        }
    };

    auto compute = [&](int c, int buf) {
        const _Float16* Bb = Blds + buf * BSZ;
        const _Float16* Ab = Alds + buf * ASZ;
#pragma unroll
        for (int ks = 0; ks < 2; ++ks) {
            const int subb = ks * 4 + quad;
            const _Float16* brow = Bb + subb * BROW + (wave * 16 + lo) * 8;
            f16x8 b0 = *(const f16x8*)(brow);
            f16x8 b1 = *(const f16x8*)(brow + 8 * BROW);
            f16x8 b2 = *(const f16x8*)(brow + 16 * BROW);
            f16x8 af[MT];
#pragma unroll
            for (int mt = 0; mt < MT; ++mt)
                af[mt] = *(const f16x8*)(Ab + subb * AROW + (mt * 16 + lo) * 8);
#pragma unroll
            for (int mt = 0; mt < MT; ++mt)
                acc[mt][0] = __builtin_amdgcn_mfma_f32_16x16x32_f16(af[mt], b0, acc[mt][0], 0, 0, 0);
#pragma unroll
            for (int mt = 0; mt < MT; ++mt)
                acc[mt][1] = __builtin_amdgcn_mfma_f32_16x16x32_f16(af[mt], b1, acc[mt][1], 0, 0, 0);
            if (c < 4) {
#pragma unroll
                for (int mt = 0; mt < MT; ++mt)
                    acc[mt][2] = __builtin_amdgcn_mfma_f32_16x16x32_f16(af[mt], b2, acc[mt][2], 0, 0, 0);
            } else {
#pragma unroll
                for (int mt = 0; mt < MT; ++mt)
                    acc[mt][3] = __builtin_amdgcn_mfma_f32_16x16x32_f16(af[mt], b2, acc[mt][3], 0, 0, 0);
            }
        }
        // capture hin from LDS while this chunk holds our dim-columns of Hsrc
        if (has_h && c == 4 + d0b) {
            const _Float16* Ab2 = Alds + buf * ASZ;
            const int colw = wave * 16 + lo;
            const int sub = colw >> 3, j = colw & 7;
#pragma unroll
            for (int mt = 0; mt < MT; ++mt)
#pragma unroll
                for (int r = 0; r < 4; ++r)
                    hinv[mt][r] = (float)Ab2[sub * AROW + (mt * 16 + quad * 4 + r) * 8 + j];
        }
    };

    if constexpr (MT == 8) {
        // ---- round-1 proven: double-buffer, one __syncthreads per chunk ----
        issueB(0, 0);
        issueA(0, 0);
        for (int c = 0; c < nch; ++c) {
            __syncthreads();              // drains A(c),B(c); frees (c+1)-parity buffers
            if (c + 1 < nch) {
                issueB(c + 1, (c + 1) & 1);
                issueA(c + 1, (c + 1) & 1);
            }
            compute(c, c & 1);
        }
    } else {
        // ---- tail: triple-buffer, depth-2 prefetch, counted vmcnt ----
        // per-wave DMA per chunk: 6 B + 2 A = 8  ->  WAITV(8) keeps chunk c+1
        // in flight while draining chunk c.
        issueB(0, 0); issueA(0, 0);
        issueB(1, 1); issueA(1, 1);
        for (int c = 0; c < nch; ++c) {
            if (c < nch - 1) WAITV(8); else WAITV(0);
            __builtin_amdgcn_s_barrier();
            __builtin_amdgcn_sched_barrier(0);
            if (c + 2 < nch) {
                int buf = (c + 2) % 3;
                issueB(c + 2, buf);
                issueA(c + 2, buf);
            }
            compute(c, c % 3);
        }
    }

    // ---- epilogue: compute h', stage via Alds, coalesced tiled stores ----
    const int ld = wave * 16 + lo;
    const int d  = d0b * 64 + ld;
    const float brz0 = BC[d];        // bir+bhr
    const float brz1 = BC[256 + d];  // biz+bhz
    const float bni  = BC[512 + d];  // bin
    const float bnh  = BC[768 + d];  // bhn
    constexpr int SROW = 72;         // staging row stride (16-B aligned rows)
    constexpr int PR   = MT * 8;     // pair-rows per block
    __syncthreads();                 // all waves done reading Alds chunk data
#pragma unroll
    for (int mt = 0; mt < MT; ++mt) {
        const int lr0 = mt * 16 + quad * 4;
        float hq[4];
#pragma unroll
        for (int r = 0; r < 4; ++r) {
            float hin = has_h ? hinv[mt][r] : 0.f;
            float rg = 1.f / (1.f + __expf(-(acc[mt][0][r] + brz0)));
            float zg = 1.f / (1.f + __expf(-(acc[mt][1][r] + brz1)));
            float ex = __expf(2.f * (acc[mt][2][r] + bni + rg * (acc[mt][3][r] + bnh)));
            float nv = 1.f - 2.f / (ex + 1.f);
            hq[r] = (1.f - zg) * nv + zg * hin;
            int lr = lr0 + r;
            if (Hout) {
                Alds[lr * SROW + ld] = (_Float16)hq[r];
            } else {
                Alds[(((lr & 1) * PR) + (lr >> 1)) * SROW + ld] =
                    (_Float16)(0.5f * (hin + hq[r]));
            }
        }
        if (!Hout) {
            Alds[(2 * PR + (lr0 >> 1)) * SROW + ld]     = (_Float16)(0.5f * (hq[0] + hq[1]));
            Alds[(2 * PR + (lr0 >> 1) + 1) * SROW + ld] = (_Float16)(0.5f * (hq[2] + hq[3]));
        }
    }
    __syncthreads();

    if (Hout) {
        constexpr int NU = MT * 128;                 // 16-B units (MT*16 rows x 64 dims)
#pragma unroll
        for (int i = 0; i < NU / 256; ++i) {
            int uid = i * 256 + tid;
            int r = uid & 63, sub = (uid >> 6) & 7, mh = uid >> 9;
            f16x8 v = *(const f16x8*)&Alds[(mh * 64 + r) * SROW + sub * 8];
            *(f16x8*)(Hout + tile_off(bm * (MT / 4) + mh, d0b, sub) + r * 8) = v;
        }
    } else {
        constexpr int NU = 3 * PR * 8;               // Ee, Eo, HP units
        const int rbE  = (MT == 8) ? bm : (bm >> 1);
        const int roff = (MT == 8) ? 0 : (bm & 1) * 32;
#pragma unroll
        for (int i = 0; i < NU / 256; ++i) {
            int uid = i * 256 + tid;
            int pr   = uid & (PR - 1);
            int rest = uid / PR;
            int sub = rest & 7, buf = rest >> 3;     // 0=Ee 1=Eo 2=HP
            f16x8 v = *(const f16x8*)&Alds[(buf * PR + pr) * SROW + sub * 8];
            _Float16* dst = (buf == 0) ? Ee : (buf == 1) ? Eo : HP;
            *(f16x8*)(dst + tile_off(rbE, d0b, sub) + (roff + pr) * 8) = v;
        }
    }
}

__global__ __launch_bounds__(256) void final_out(
    const _Float16* __restrict__ XE, const _Float16* __restrict__ XO,
    float* __restrict__ out)
{
    int i = blockIdx.x * 256 + threadIdx.x;   // 8192
    int j = i >> 8, col = i & 255;
    const _Float16* src = (j & 1) ? XO : XE;
    int r = j >> 1;                            // 0..15, all in tile 0
    out[i] = (float)src[tile_off(0, col >> 6, (col >> 3) & 7) + r * 8 + (col & 7)];
}

extern "C" void kernel_launch(void* const* d_in, const int* in_sizes, int n_in,
                              void* d_out, int out_size, void* d_ws, size_t ws_size,
                              hipStream_t stream) {
    const float* leaf = (const float*)d_in[0];
    const float* Wih  = (const float*)d_in[1];
    const float* Whh  = (const float*)d_in[2];
    const float* bih  = (const float*)d_in[3];
    const float* bhh  = (const float*)d_in[4];

    char* ws = (char*)d_ws;
    _Float16* WPp = (_Float16*)ws;                         //  1 MB
    _Float16* XAe = (_Float16*)(ws + (1ull  << 20));       // 32 MB
    _Float16* XAo = (_Float16*)(ws + (33ull << 20));       // 32 MB
    _Float16* XBe = (_Float16*)(ws + (65ull << 20));       // 16 MB
    _Float16* XBo = (_Float16*)(ws + (81ull << 20));       // 16 MB
    _Float16* H1  = (_Float16*)(ws + (97ull << 20));       // 32 MB
    _Float16* HPb = (_Float16*)(ws + (129ull << 20));      // 16 MB
    float*    BCp = (float*)(ws + (145ull << 20));         //  4 KB

    prepack_weights<<<2049, 256, 0, stream>>>(Wih, Whh, bih, bhh, WPp, BCp);
    convert_split<<<16384, 256, 0, stream>>>(leaf, XAe, XAo);

    _Float16 *XeC = XAe, *XoC = XAo, *XeN = XBe, *XoN = XBo;
    const _Float16* hp = nullptr;
    int M = 65536;
    for (int lev = 0; lev < 12; ++lev) {
        if (M >= 8192) {
            int grid = (M / 128) * 4;
            gru_cell<8, true><<<grid, 256, 0, stream>>>(XeC, hp, WPp, BCp,
                                                        H1, nullptr, nullptr, nullptr, M);
            gru_cell<8, true><<<grid, 256, 0, stream>>>(XoC, H1, WPp, BCp,
                                                        nullptr, XeN, XoN, HPb, M);
        } else {
            int nbm = (M + 63) / 64;
            int grid = nbm * 4;
            if ((nbm & 7) == 0) {
                gru_cell<4, true><<<grid, 256, 0, stream>>>(XeC, hp, WPp, BCp,
                                                            H1, nullptr, nullptr, nullptr, M);
                gru_cell<4, true><<<grid, 256, 0, stream>>>(XoC, H1, WPp, BCp,
                                                            nullptr, XeN, XoN, HPb, M);
            } else {
                gru_cell<4, false><<<grid, 256, 0, stream>>>(XeC, hp, WPp, BCp,
                                                             H1, nullptr, nullptr, nullptr, M);
                gru_cell<4, false><<<grid, 256, 0, stream>>>(XoC, H1, WPp, BCp,
                                                             nullptr, XeN, XoN, HPb, M);
            }
        }
        hp = HPb;
        _Float16* t;
        t = XeC; XeC = XeN; XeN = t;
        t = XoC; XoC = XoN; XoN = t;
        M >>= 1;
    }
    final_out<<<32, 256, 0, stream>>>(XeC, XoC, (float*)d_out);
}

// Round 4
// 662.898 us; speedup vs baseline: 1.1312x; 1.0048x over previous
//
#include <hip/hip_runtime.h>
#include <hip/hip_bf16.h>
#include <stdint.h>

typedef _Float16 f16x8 __attribute__((ext_vector_type(8)));
typedef _Float16 f16x4 __attribute__((ext_vector_type(4)));
typedef float    f32x4 __attribute__((ext_vector_type(4)));

// async 16-B global->LDS DMA: per-lane global src, dest = wave-uniform base + lane*16
#define GLDS16(gptr, lptr) \
  __builtin_amdgcn_global_load_lds((const __attribute__((address_space(1))) void*)(gptr), \
                                   (__attribute__((address_space(3))) void*)(lptr), 16, 0, 0)

// counted vmcnt wait (literal immediate), full memory clobber so LDS reads /
// DMA issues cannot cross it (rule #18)
#define WAITV(N) asm volatile("s_waitcnt vmcnt(" #N ")" ::: "memory")

// ---- tiled ("DMA-image") activation layout ----
// element (row, col) lives at:
//   addr = ((rb*4 + c)*8 + sub)*512 + r*8 + j     (halves)
// with rb=row>>6, r=row&63, c=col>>6, sub=(col>>3)&7, j=col&7.
// One (rb,c,sub) unit = 64 rows x 8 cols = 512 halves = 1 KB contiguous,
// exactly the order gru_cell's A-DMA fills LDS -> fully coalesced loads.
__device__ __forceinline__ int tile_off(int rb, int c, int sub) {
    return ((rb * 4 + c) * 8 + sub) * 512;
}

// WP layout: [c(8)][d0b(4)][g(4)][sub(8)][nl(64)][j(8)] halves.
// element = W(group g, dim d = d0b*64+nl, k = c*64+sub*8+j)
// Block 2048 packs BC[1024]: [d]=bih[d]+bhh[d], [256+d]=bih[256+d]+bhh[256+d],
//                            [512+d]=bih[512+d], [768+d]=bhh[512+d]
__global__ __launch_bounds__(256) void prepack_weights(
    const float* __restrict__ Wih, const float* __restrict__ Whh,
    const float* __restrict__ bih, const float* __restrict__ bhh,
    _Float16* __restrict__ WP, float* __restrict__ BC)
{
    if (blockIdx.x == 2048) {
        int i = threadIdx.x;
        BC[i]       = bih[i] + bhh[i];
        BC[256 + i] = bih[256 + i] + bhh[256 + i];
        BC[512 + i] = bih[512 + i];
        BC[768 + i] = bhh[512 + i];
        return;
    }
    int idx = blockIdx.x * 256 + threadIdx.x;   // 524288 total
    int j   = idx & 7;
    int nl  = (idx >> 3) & 63;
    int sub = (idx >> 9) & 7;
    int g   = (idx >> 12) & 3;
    int d0b = (idx >> 14) & 3;
    int c   = idx >> 16;
    int k = c * 64 + sub * 8 + j;
    int d = d0b * 64 + nl;
    float v = 0.f;
    if (g == 0)      v = (k < 256) ? Wih[d * 256 + k]         : Whh[d * 256 + (k - 256)];
    else if (g == 1) v = (k < 256) ? Wih[(256 + d) * 256 + k] : Whh[(256 + d) * 256 + (k - 256)];
    else if (g == 2) v = (k < 256) ? Wih[(512 + d) * 256 + k] : 0.f;
    else             v = (k >= 256) ? Whh[(512 + d) * 256 + (k - 256)] : 0.f;
    WP[idx] = (_Float16)v;
}

// fp32 leaf -> fp16, split even/odd rows into TILED XE / XO buffers.
__global__ __launch_bounds__(256) void convert_split(
    const float* __restrict__ leaf, _Float16* __restrict__ XE, _Float16* __restrict__ XO)
{
    int g = blockIdx.x * 256 + threadIdx.x;     // 131072 rows * 32 units
    int u = g & 31;                              // 16-B col unit: cols u*8 .. u*8+7
    int row = g >> 5;
    const float* src = leaf + (size_t)row * 256 + u * 8;
    float4 a = *(const float4*)src;
    float4 b = *(const float4*)(src + 4);
    f16x8 p;
    p[0] = (_Float16)a.x; p[1] = (_Float16)a.y; p[2] = (_Float16)a.z; p[3] = (_Float16)a.w;
    p[4] = (_Float16)b.x; p[5] = (_Float16)b.y; p[6] = (_Float16)b.z; p[7] = (_Float16)b.w;
    int ro = row >> 1;
    _Float16* dst = (row & 1) ? XO : XE;
    *(f16x8*)(dst + tile_off(ro >> 6, u >> 3, u & 7) + (ro & 63) * 8) = p;
}

// GRU cell. A (activations) staged via async DMA into LDS; B (weights) read
// DIRECTLY from L2 into registers per wave (no B staging at all):
//   - per chunk per wave: 6 coalesced f16x8 loads from WP (L2-resident 1 MB)
//   - B loads issued BEFORE the A-prefetch DMAs (pinned by sched_barrier) so
//     the compiler's wait for B is a counted vmcnt leaving A in flight.
//   MT=8: double-buffered A, one __syncthreads per chunk (round-1 proven).
//   MT=4: triple-buffered A, depth-2 prefetch, counted WAITV(2).
// cell1 (Hout != null): h' -> Hout tiles       (hin = Hsrc or 0)
// cell2 (Hout == null): E=0.5(hin+h') -> Ee/Eo tiles; HP = pair-avg(h') tiles
template<int MT, bool SWIZ>
__global__ __launch_bounds__(256, (MT == 8) ? 2 : 3) void gru_cell(
    const _Float16* __restrict__ Xsrc,
    const _Float16* __restrict__ Hsrc,
    const _Float16* __restrict__ WP,
    const float* __restrict__ BC,
    _Float16* __restrict__ Hout,
    _Float16* __restrict__ Ee, _Float16* __restrict__ Eo, _Float16* __restrict__ HP,
    int M)
{
    (void)M;
    constexpr int NBUF = (MT == 8) ? 2 : 3;
    constexpr int AROW = MT * 16 * 8;       // halves per A sub-row
    constexpr int ASZ  = 8 * AROW;          // MT=8: 16 KB, MT=4: 8 KB
    __shared__ __align__(16) _Float16 Alds[NBUF * ASZ];   // MT=8: 32 KB, MT=4: 24 KB

    const int tid  = threadIdx.x;
    int bm, d0b;
    if (SWIZ) {  // siblings (same bm, 4 d0b) share blockIdx%8 -> same XCD
        int xcd = blockIdx.x & 7, slot = blockIdx.x >> 3;
        d0b = slot & 3;
        bm  = (slot >> 2) * 8 + xcd;
    } else {
        bm = blockIdx.x >> 2; d0b = blockIdx.x & 3;
    }
    const int wave = tid >> 6, lane = tid & 63;
    const int quad = lane >> 4, lo = lane & 15;

    const bool has_h = (Hsrc != nullptr);
    const int nch = has_h ? 8 : 4;

    f32x4 acc[MT][4];
#pragma unroll
    for (int a = 0; a < MT; ++a)
#pragma unroll
        for (int b = 0; b < 4; ++b) acc[a][b] = (f32x4){0.f, 0.f, 0.f, 0.f};
    f16x4 hinvh[MT];                        // packed hin (saves 16 VGPRs vs float)

    // 6 direct B-fragment loads (this wave's own operands, 4x256B segments each)
    auto loadB = [&](int c, f16x8 (&bb)[2][3]) {
        const size_t cb = (size_t)(c * 4 + d0b) * 4;
        const int col = (wave * 16 + lo) * 8;
#pragma unroll
        for (int ks = 0; ks < 2; ++ks) {
            const int subb = ks * 4 + quad;
#pragma unroll
            for (int slot = 0; slot < 3; ++slot) {
                int g = (slot == 2) ? ((c < 4) ? 2 : 3) : slot;
                bb[ks][slot] = *(const f16x8*)(WP + ((cb + g) * 8 + subb) * 512 + col);
            }
        }
    };

    auto issueA = [&](int c, int buf) {   // 2*MT coalesced 1-KB DMA issues, MT/2 per wave
        const _Float16* base = (c < 4) ? Xsrc : Hsrc;
        const int cc = c & 3;
        _Float16* Ab = Alds + buf * ASZ;
        constexpr int ND = MT / 2;
#pragma unroll
        for (int i = 0; i < ND; ++i) {
            int ai = wave * ND + i;
            int sub = (MT == 8) ? (ai >> 1) : ai;
            int mh  = (MT == 8) ? (ai & 1) : 0;
            GLDS16(base + tile_off(bm * (MT / 4) + mh, cc, sub) + lane * 8,
                   Ab + sub * AROW + mh * 512);
        }
    };

    // mt-outer MFMA order: 1 A-frag live at a time; same-acc reuse distance 3*MT
    auto compute = [&](int c, int buf, f16x8 (&bb)[2][3]) {
        const _Float16* Ab = Alds + buf * ASZ;
#pragma unroll
        for (int ks = 0; ks < 2; ++ks) {
            const int subb = ks * 4 + quad;
#pragma unroll
            for (int mt = 0; mt < MT; ++mt) {
                f16x8 a = *(const f16x8*)(Ab + subb * AROW + (mt * 16 + lo) * 8);
                acc[mt][0] = __builtin_amdgcn_mfma_f32_16x16x32_f16(a, bb[ks][0], acc[mt][0], 0, 0, 0);
                acc[mt][1] = __builtin_amdgcn_mfma_f32_16x16x32_f16(a, bb[ks][1], acc[mt][1], 0, 0, 0);
                if (c < 4)
                    acc[mt][2] = __builtin_amdgcn_mfma_f32_16x16x32_f16(a, bb[ks][2], acc[mt][2], 0, 0, 0);
                else
                    acc[mt][3] = __builtin_amdgcn_mfma_f32_16x16x32_f16(a, bb[ks][2], acc[mt][3], 0, 0, 0);
            }
        }
        // capture hin from LDS while this chunk holds our dim-columns of Hsrc
        if (has_h && c == 4 + d0b) {
            const int colw = wave * 16 + lo;
            const int sub = colw >> 3, j = colw & 7;
#pragma unroll
            for (int mt = 0; mt < MT; ++mt)
#pragma unroll
                for (int r = 0; r < 4; ++r)
                    hinvh[mt][r] = Ab[sub * AROW + (mt * 16 + quad * 4 + r) * 8 + j];
        }
    };

    if constexpr (MT == 8) {
        // ---- proven: A double-buffer, one __syncthreads per chunk ----
        issueA(0, 0);
        for (int c = 0; c < nch; ++c) {
            __syncthreads();              // drains A(c); frees (c+1)-parity buffer
            f16x8 bb[2][3];
            loadB(c, bb);                 // issued BEFORE A-prefetch -> counted wait
            __builtin_amdgcn_sched_barrier(0);
            if (c + 1 < nch) issueA(c + 1, (c + 1) & 1);
            compute(c, c & 1, bb);
        }
    } else {
        // ---- tail: A triple-buffer, depth-2 prefetch, counted vmcnt ----
        // per-wave A DMA per chunk = 2 -> WAITV(2) keeps chunk c+1 in flight.
        issueA(0, 0); issueA(1, 1);
        for (int c = 0; c < nch; ++c) {
            if (c < nch - 1) WAITV(2); else WAITV(0);
            __builtin_amdgcn_s_barrier();
            __builtin_amdgcn_sched_barrier(0);
            f16x8 bb[2][3];
            loadB(c, bb);
            __builtin_amdgcn_sched_barrier(0);
            if (c + 2 < nch) issueA(c + 2, (c + 2) % 3);
            compute(c, c % 3, bb);
        }
    }

    // ---- epilogue: compute h', stage via Alds, coalesced tiled stores ----
    const int ld = wave * 16 + lo;
    const int d  = d0b * 64 + ld;
    const float brz0 = BC[d];        // bir+bhr
    const float brz1 = BC[256 + d];  // biz+bhz
    const float bni  = BC[512 + d];  // bin
    const float bnh  = BC[768 + d];  // bhn
    constexpr int SROW = 72;         // staging row stride (16-B aligned rows)
    constexpr int PR   = MT * 8;     // pair-rows per block
    __syncthreads();                 // all waves done reading Alds chunk data
#pragma unroll
    for (int mt = 0; mt < MT; ++mt) {
        const int lr0 = mt * 16 + quad * 4;
        float hq[4];
#pragma unroll
        for (int r = 0; r < 4; ++r) {
            float hin = has_h ? (float)hinvh[mt][r] : 0.f;
            float rg = 1.f / (1.f + __expf(-(acc[mt][0][r] + brz0)));
            float zg = 1.f / (1.f + __expf(-(acc[mt][1][r] + brz1)));
            float ex = __expf(2.f * (acc[mt][2][r] + bni + rg * (acc[mt][3][r] + bnh)));
            float nv = 1.f - 2.f / (ex + 1.f);
            hq[r] = (1.f - zg) * nv + zg * hin;
            int lr = lr0 + r;
            if (Hout) {
                Alds[lr * SROW + ld] = (_Float16)hq[r];
            } else {
                Alds[(((lr & 1) * PR) + (lr >> 1)) * SROW + ld] =
                    (_Float16)(0.5f * (hin + hq[r]));
            }
        }
        if (!Hout) {
            Alds[(2 * PR + (lr0 >> 1)) * SROW + ld]     = (_Float16)(0.5f * (hq[0] + hq[1]));
            Alds[(2 * PR + (lr0 >> 1) + 1) * SROW + ld] = (_Float16)(0.5f * (hq[2] + hq[3]));
        }
    }
    __syncthreads();

    if (Hout) {
        constexpr int NU = MT * 128;                 // 16-B units (MT*16 rows x 64 dims)
#pragma unroll
        for (int i = 0; i < NU / 256; ++i) {
            int uid = i * 256 + tid;
            int r = uid & 63, sub = (uid >> 6) & 7, mh = uid >> 9;
            f16x8 v = *(const f16x8*)&Alds[(mh * 64 + r) * SROW + sub * 8];
            *(f16x8*)(Hout + tile_off(bm * (MT / 4) + mh, d0b, sub) + r * 8) = v;
        }
    } else {
        constexpr int NU = 3 * PR * 8;               // Ee, Eo, HP units
        const int rbE  = (MT == 8) ? bm : (bm >> 1);
        const int roff = (MT == 8) ? 0 : (bm & 1) * 32;
#pragma unroll
        for (int i = 0; i < NU / 256; ++i) {
            int uid = i * 256 + tid;
            int pr   = uid & (PR - 1);
            int rest = uid / PR;
            int sub = rest & 7, buf = rest >> 3;     // 0=Ee 1=Eo 2=HP
            f16x8 v = *(const f16x8*)&Alds[(buf * PR + pr) * SROW + sub * 8];
            _Float16* dst = (buf == 0) ? Ee : (buf == 1) ? Eo : HP;
            *(f16x8*)(dst + tile_off(rbE, d0b, sub) + (roff + pr) * 8) = v;
        }
    }
}

__global__ __launch_bounds__(256) void final_out(
    const _Float16* __restrict__ XE, const _Float16* __restrict__ XO,
    float* __restrict__ out)
{
    int i = blockIdx.x * 256 + threadIdx.x;   // 8192
    int j = i >> 8, col = i & 255;
    const _Float16* src = (j & 1) ? XO : XE;
    int r = j >> 1;                            // 0..15, all in tile 0
    out[i] = (float)src[tile_off(0, col >> 6, (col >> 3) & 7) + r * 8 + (col & 7)];
}

extern "C" void kernel_launch(void* const* d_in, const int* in_sizes, int n_in,
                              void* d_out, int out_size, void* d_ws, size_t ws_size,
                              hipStream_t stream) {
    const float* leaf = (const float*)d_in[0];
    const float* Wih  = (const float*)d_in[1];
    const float* Whh  = (const float*)d_in[2];
    const float* bih  = (const float*)d_in[3];
    const float* bhh  = (const float*)d_in[4];

    char* ws = (char*)d_ws;
    _Float16* WPp = (_Float16*)ws;                         //  1 MB
    _Float16* XAe = (_Float16*)(ws + (1ull  << 20));       // 32 MB
    _Float16* XAo = (_Float16*)(ws + (33ull << 20));       // 32 MB
    _Float16* XBe = (_Float16*)(ws + (65ull << 20));       // 16 MB
    _Float16* XBo = (_Float16*)(ws + (81ull << 20));       // 16 MB
    _Float16* H1  = (_Float16*)(ws + (97ull << 20));       // 32 MB
    _Float16* HPb = (_Float16*)(ws + (129ull << 20));      // 16 MB
    float*    BCp = (float*)(ws + (145ull << 20));         //  4 KB

    prepack_weights<<<2049, 256, 0, stream>>>(Wih, Whh, bih, bhh, WPp, BCp);
    convert_split<<<16384, 256, 0, stream>>>(leaf, XAe, XAo);

    _Float16 *XeC = XAe, *XoC = XAo, *XeN = XBe, *XoN = XBo;
    const _Float16* hp = nullptr;
    int M = 65536;
    for (int lev = 0; lev < 12; ++lev) {
        if (M >= 8192) {
            int grid = (M / 128) * 4;
            gru_cell<8, true><<<grid, 256, 0, stream>>>(XeC, hp, WPp, BCp,
                                                        H1, nullptr, nullptr, nullptr, M);
            gru_cell<8, true><<<grid, 256, 0, stream>>>(XoC, H1, WPp, BCp,
                                                        nullptr, XeN, XoN, HPb, M);
        } else {
            int nbm = (M + 63) / 64;
            int grid = nbm * 4;
            if ((nbm & 7) == 0) {
                gru_cell<4, true><<<grid, 256, 0, stream>>>(XeC, hp, WPp, BCp,
                                                            H1, nullptr, nullptr, nullptr, M);
                gru_cell<4, true><<<grid, 256, 0, stream>>>(XoC, H1, WPp, BCp,
                                                            nullptr, XeN, XoN, HPb, M);
            } else {
                gru_cell<4, false><<<grid, 256, 0, stream>>>(XeC, hp, WPp, BCp,
                                                             H1, nullptr, nullptr, nullptr, M);
                gru_cell<4, false><<<grid, 256, 0, stream>>>(XoC, H1, WPp, BCp,
                                                             nullptr, XeN, XoN, HPb, M);
            }
        }
        hp = HPb;
        _Float16* t;
        t = XeC; XeC = XeN; XeN = t;
        t = XoC; XoC = XoN; XoN = t;
        M >>= 1;
    }
    final_out<<<32, 256, 0, stream>>>(XeC, XoC, (float*)d_out);
}